// Round 1
// baseline (558.569 us; speedup 1.0000x reference)
//
#include <hip/hip_runtime.h>

typedef unsigned short u16;
typedef __bf16 bf16x8 __attribute__((ext_vector_type(8)));
typedef float  f32x4  __attribute__((ext_vector_type(4)));

__device__ __forceinline__ u16 f2b(float f) {
    unsigned u = __float_as_uint(f);
    return (u16)((u + 0x7FFFu + ((u >> 16) & 1u)) >> 16);  // RNE f32->bf16
}
__device__ __forceinline__ float b2f(u16 b) {
    return __uint_as_float(((unsigned)b) << 16);
}

// ---------------------------------------------------------------------------
// prep: pp[r][j]  = pos_table[r] . W_pos_w[j,128:256] + W_pos_b[j]   (fp32)
//       wb1[j][k] = bf16(W_pos_w[j][k])        (k<128, GEMM1 B operand)
//       wb2[j][k] = bf16(W2[j][k])             (GEMM2 B operand)
//       w1t[k][j] = bf16(W1[j][k])             (transposed, coalesced g1 reads)
// ---------------------------------------------------------------------------
__global__ __launch_bounds__(128) void prep_kernel(
    const float* __restrict__ pos_table, const float* __restrict__ Wpw,
    const float* __restrict__ Wpb, const float* __restrict__ W1,
    const float* __restrict__ W2,
    float* __restrict__ pp, u16* __restrict__ wb1, u16* __restrict__ wb2,
    u16* __restrict__ w1t)
{
    const int b = blockIdx.x, t = threadIdx.x;
    if (b < 65) {
        float acc = Wpb[t];
        const float* pr = pos_table + b * 128;
        const float* wr = Wpw + t * 256 + 128;
        #pragma unroll 8
        for (int k = 0; k < 128; ++k) acc += pr[k] * wr[k];
        pp[b * 128 + t] = acc;
    } else {
        const int j = b - 65;                      // 0..127
        wb1[j * 128 + t] = f2b(Wpw[j * 256 + t]);
        wb2[j * 128 + t] = f2b(W2[j * 128 + t]);
        w1t[t * 128 + j] = f2b(W1[j * 128 + t]);
    }
}

// ---------------------------------------------------------------------------
// fused: one block = one session (64 tokens x 128 hidden)
// ---------------------------------------------------------------------------
__global__ __launch_bounds__(256) void fused_kernel(
    const float* __restrict__ hidden, const int* __restrict__ rpos,
    const float* __restrict__ W1b, const float* __restrict__ W2b,
    const float* __restrict__ qw, const float* __restrict__ qb,
    const float* __restrict__ pp, const u16* __restrict__ wb1g,
    const u16* __restrict__ wb2g, const u16* __restrict__ w1t,
    float* __restrict__ out)
{
    // 64 rows x 136 bf16 (pad +8 breaks 256B bank stride); reused for ph
    __shared__ u16 hbf[64 * 136];           // 17408 B
    __shared__ u16 wb[128 * 136];           // 34816 B (wb1 then wb2)
    __shared__ float meanv[128];
    __shared__ float g1s[128];
    __shared__ float qws[128];
    __shared__ float alphas[64];
    __shared__ int   rps[64];
    __shared__ float partf[256];            // total ~55.3 KB -> 2 blocks/CU

    const int tid = threadIdx.x;
    const int s = blockIdx.x;
    const int w = tid >> 6;                 // wave 0..3 (rows 16w..16w+15)
    const int l = tid & 63;
    const int c = l & 15;                   // MFMA A-row / B-col / D-col
    const int g = l >> 4;                   // quad: k-chunk, D-row group
    const float* hsrc = hidden + (size_t)s * (64 * 128);

    // ---- stage hidden (fp32 global -> bf16 LDS), coalesced float4
    #pragma unroll
    for (int i = 0; i < 8; ++i) {
        const int i4 = tid + i * 256;                 // float4 index 0..2047
        const float4 v = ((const float4*)hsrc)[i4];
        const int e = i4 * 4, row = e >> 7, col = e & 127;
        u16* d = &hbf[row * 136 + col];
        d[0] = f2b(v.x); d[1] = f2b(v.y); d[2] = f2b(v.z); d[3] = f2b(v.w);
    }
    // ---- stage wb1 (bf16 ws -> padded LDS), 16B chunks
    #pragma unroll
    for (int i = 0; i < 8; ++i) {
        const int ch = tid + i * 256;                 // 0..2047 chunks of 8
        const int e = ch * 8, row = e >> 7, col = e & 127;
        *(uint4*)&wb[row * 136 + col] = ((const uint4*)wb1g)[ch];
    }
    if (tid < 64)  rps[tid] = rpos[s * 64 + tid];
    if (tid < 128) qws[tid] = qw[tid];
    __syncthreads();

    // ---- per-session mean (bf16 source; quant error negligible after /64)
    if (tid < 128) {
        float m = 0.f;
        #pragma unroll 8
        for (int t = 0; t < 64; ++t) m += b2f(hbf[t * 136 + tid]);
        meanv[tid] = m * (1.f / 64.f);
    }
    __syncthreads();   // mean visible; also fences hbf reads before overwrite

    // ---- g1 = mean @ W1^T + W1_b + W2_b (fp32 acc; runs on waves 0-1 while
    //      waves 2-3 start GEMM1; visibility via the post-GEMM1 barrier)
    if (tid < 128) {
        float acc = W1b[tid] + W2b[tid];
        #pragma unroll 8
        for (int k = 0; k < 128; ++k) acc += meanv[k] * b2f(w1t[k * 128 + tid]);
        g1s[tid] = acc;
    }

    // ---- GEMM1: ph = tanh(hidden @ Wpa^T + pp[rp])   M=16/wave, N=128, K=128
    bf16x8 afr[4];
    #pragma unroll
    for (int kk = 0; kk < 4; ++kk)
        afr[kk] = *(const bf16x8*)&hbf[(16 * w + c) * 136 + kk * 32 + g * 8];
    f32x4 acc1[8] = {};
    #pragma unroll
    for (int n = 0; n < 8; ++n) {
        #pragma unroll
        for (int kk = 0; kk < 4; ++kk) {
            const bf16x8 bfr = *(const bf16x8*)&wb[(16 * n + c) * 136 + kk * 32 + g * 8];
            acc1[n] = __builtin_amdgcn_mfma_f32_16x16x32_bf16(afr[kk], bfr, acc1[n], 0, 0, 0);
        }
    }
    int rp4[4];
    #pragma unroll
    for (int r = 0; r < 4; ++r) rp4[r] = rps[16 * w + 4 * g + r];
    #pragma unroll
    for (int n = 0; n < 8; ++n) {
        const int j = 16 * n + c;
        #pragma unroll
        for (int r = 0; r < 4; ++r) {
            const float v = acc1[n][r] + pp[rp4[r] * 128 + j];
            const float e2 = exp2f(v * 2.885390081777927f);     // e^(2v)
            const float th = 1.f - 2.f / (e2 + 1.f);            // tanh(v)
            // in-place: D rows (4g+r) are within this wave's own 16-row tile
            hbf[(16 * w + 4 * g + r) * 136 + j] = f2b(th);
        }
    }
    __syncthreads();   // all wb1 reads done, ph committed

    // ---- restage wb <- wb2
    #pragma unroll
    for (int i = 0; i < 8; ++i) {
        const int ch = tid + i * 256;
        const int e = ch * 8, row = e >> 7, col = e & 127;
        *(uint4*)&wb[row * 136 + col] = ((const uint4*)wb2g)[ch];
    }
    __syncthreads();

    // ---- GEMM2: gate = sigmoid(g1 + ph @ W2^T); alpha = gate.qw + qb
    bf16x8 af2[4];
    #pragma unroll
    for (int kk = 0; kk < 4; ++kk)
        af2[kk] = *(const bf16x8*)&hbf[(16 * w + c) * 136 + kk * 32 + g * 8];
    f32x4 acc2[8] = {};
    #pragma unroll
    for (int n = 0; n < 8; ++n) {
        #pragma unroll
        for (int kk = 0; kk < 4; ++kk) {
            const bf16x8 bfr = *(const bf16x8*)&wb[(16 * n + c) * 136 + kk * 32 + g * 8];
            acc2[n] = __builtin_amdgcn_mfma_f32_16x16x32_bf16(af2[kk], bfr, acc2[n], 0, 0, 0);
        }
    }
    float prt[4] = {0.f, 0.f, 0.f, 0.f};
    #pragma unroll
    for (int n = 0; n < 8; ++n) {
        const int j = 16 * n + c;
        const float g1j = g1s[j], qwj = qws[j];
        #pragma unroll
        for (int r = 0; r < 4; ++r) {
            const float x = acc2[n][r] + g1j;
            const float gate = 1.f / (1.f + exp2f(-1.4426950408889634f * x));
            prt[r] += gate * qwj;
        }
    }
    // reduce over the 16 D-columns (lanes c=0..15 within each quad-group)
    #pragma unroll
    for (int msk = 1; msk <= 8; msk <<= 1) {
        #pragma unroll
        for (int r = 0; r < 4; ++r) prt[r] += __shfl_xor(prt[r], msk, 64);
    }
    if (c == 0) {
        const float qbv = qb[0];
        #pragma unroll
        for (int r = 0; r < 4; ++r) alphas[16 * w + 4 * g + r] = prt[r] + qbv;
    }
    __syncthreads();

    // ---- out[s] = sum_t alpha_t * hidden[t]  (fp32 from global; L2-hot)
    {
        const int h = tid & 127, p = tid >> 7;
        float accf = 0.f;
        #pragma unroll 8
        for (int t = 32 * p; t < 32 * p + 32; ++t)
            accf += alphas[t] * hsrc[t * 128 + h];
        partf[p * 128 + h] = accf;
    }
    __syncthreads();
    if (tid < 128) out[(size_t)s * 128 + tid] = partf[tid] + partf[128 + tid];
}

// ---------------------------------------------------------------------------
extern "C" void kernel_launch(void* const* d_in, const int* in_sizes, int n_in,
                              void* d_out, int out_size, void* d_ws, size_t ws_size,
                              hipStream_t stream)
{
    const float* hidden    = (const float*)d_in[0];
    const float* pos_table = (const float*)d_in[1];
    const float* Wpw       = (const float*)d_in[2];
    const float* Wpb       = (const float*)d_in[3];
    const float* W1w       = (const float*)d_in[4];
    const float* W1b       = (const float*)d_in[5];
    const float* W2w       = (const float*)d_in[6];
    const float* W2b       = (const float*)d_in[7];
    const float* qw        = (const float*)d_in[8];
    const float* qb        = (const float*)d_in[9];
    const int*   rpos      = (const int*)d_in[11];
    float* out = (float*)d_out;

    const int B = in_sizes[10];              // sessions (8192)

    // workspace layout (131584 B total)
    char* wsb = (char*)d_ws;
    float* pp = (float*)wsb;                         // 65*128*4 = 33280
    u16* wb1  = (u16*)(wsb + 33280);                 // 32768
    u16* wb2  = (u16*)(wsb + 33280 + 32768);         // 32768
    u16* w1t  = (u16*)(wsb + 33280 + 2 * 32768);     // 32768

    prep_kernel<<<193, 128, 0, stream>>>(pos_table, Wpw, Wpb, W1w, W2w,
                                         pp, wb1, wb2, w1t);
    fused_kernel<<<B, 256, 0, stream>>>(hidden, rpos, W1b, W2b, qw, qb,
                                        pp, wb1, wb2, w1t, out);
}